// Round 19
// baseline (98.065 us; speedup 1.0000x reference)
//
#include <hip/hip_runtime.h>
#include <hip/hip_bf16.h>

#define BB 8
#define NN 2048
#define CC 320
#define CQ 64
#define LOG2E 1.4426950408889634f

typedef __attribute__((ext_vector_type(8)))  short bf16x8;
typedef __attribute__((ext_vector_type(4)))  float f32x4;
typedef __attribute__((ext_vector_type(16))) float f32x16;
typedef __attribute__((ext_vector_type(4)))  unsigned short us4;
typedef __attribute__((ext_vector_type(8)))  unsigned short us8;
typedef __attribute__((ext_vector_type(4)))  unsigned int u32x4;
typedef unsigned short u16;

// Layouts:
//  X3[mt=m/32][kk8=k/8][ml=m%32][8]       (bf16; lane-contiguous A-frags)
//  W3[ct=c/32][kk8=k/8][cl=c%32][8]       (bf16; lane-contiguous B-frags)
//  Q3[b][kt=k/32][cq8=cq/8][kl=k%32][8]   (bf16, pre-scaled by log2e)
//  Kb[b*N+n][cq]                          (row-major)
//  V3[b][kt8=k/8][c][8]                   (bf16, UNSCALED — read-only)
//  Lb[b*N+k]                              (f32, log2 of softmax row sum)

static __device__ __forceinline__ u16 f2b(float f) {
  unsigned u = __builtin_bit_cast(unsigned, f);
  unsigned r = (u + 0x7FFFu + ((u >> 16) & 1u)) >> 16;
  return (u16)r;
}
static __device__ __forceinline__ float b2f(u16 s) {
  unsigned u = ((unsigned)s) << 16;
  return __builtin_bit_cast(float, u);
}

static __device__ __forceinline__ f32x16 zero16() {
  f32x16 v = {0,0,0,0, 0,0,0,0, 0,0,0,0, 0,0,0,0};
  return v;
}
static __device__ __forceinline__ f32x4 zero4() {
  f32x4 v = {0,0,0,0};
  return v;
}

static __device__ __forceinline__ void gll16(const void* g, void* l) {
  __builtin_amdgcn_global_load_lds(
      (const __attribute__((address_space(1))) unsigned int*)g,
      (__attribute__((address_space(3))) unsigned int*)l, 16, 0, 0);
}

// 8 fp32 -> bf16x8 via hardware packed converts (RNE, same as f2b)
static __device__ __forceinline__ bf16x8 cvt8(float4 a, float4 b) {
  unsigned p0, p1, p2, p3;
  asm("v_cvt_pk_bf16_f32 %0, %1, %2" : "=v"(p0) : "v"(a.x), "v"(a.y));
  asm("v_cvt_pk_bf16_f32 %0, %1, %2" : "=v"(p1) : "v"(a.z), "v"(a.w));
  asm("v_cvt_pk_bf16_f32 %0, %1, %2" : "=v"(p2) : "v"(b.x), "v"(b.y));
  asm("v_cvt_pk_bf16_f32 %0, %1, %2" : "=v"(p3) : "v"(b.z), "v"(b.w));
  u32x4 w = {p0, p1, p2, p3};
  return __builtin_bit_cast(bf16x8, w);
}

// ---------------------------------------------------------------------------
// K0: fused conversion. blocks 0..511: x -> X3; blocks 512..525: W -> W3.
// grid 526 x 256.
// ---------------------------------------------------------------------------
__global__ __launch_bounds__(256) void cvt_blk(const float* __restrict__ x,
                                               const float* __restrict__ Wq,
                                               const float* __restrict__ Wk,
                                               const float* __restrict__ Wv,
                                               u16* __restrict__ X3,
                                               u16* __restrict__ W3) {
  __shared__ float xs[32][324];   // +4 pad: conflict-free transpose reads
  const int t = threadIdx.x;
  const int bid = blockIdx.x;
  const bool isX = (bid < 512);
  const int b = isX ? bid : (bid - 512);
#pragma unroll
  for (int i = 0; i < 10; ++i) {
    const int lidx = i * 256 + t;        // 0..2559 float4 units
    const int m = lidx / 80;             // 80 float4 per row
    const int kq = lidx - m * 80;
    const float* src;
    if (isX) {
      src = x + (size_t)(b * 32 + m) * CC;
    } else {
      const int row = b * 32 + m;
      src = (row < 64) ? (Wq + (size_t)row * CC)
          : (row < 128) ? (Wk + (size_t)(row - 64) * CC)
                        : (Wv + (size_t)(row - 128) * CC);
    }
    float4 v = *(const float4*)(src + kq * 4);
    *(float4*)&xs[m][kq * 4] = v;
  }
  __syncthreads();
  u16* dst0 = (isX ? X3 : W3) + (size_t)b * 10240;
#pragma unroll
  for (int i = 0; i < 5; ++i) {
    const int u = i * 256 + t;           // 0..1279: kk8*32 + ml
    const int kk8 = u >> 5, ml = u & 31;
    float4 a = *(const float4*)&xs[ml][kk8 * 8];
    float4 c = *(const float4*)&xs[ml][kk8 * 8 + 4];
    bf16x8 o = cvt8(a, c);
    *(bf16x8*)(dst0 + (size_t)u * 8) = o;
  }
}

// ---------------------------------------------------------------------------
// K1: QKV GEMM, wide 128-col wave tiles (4 MFMA per 5 loads). XCD remap.
// grid 512 x 256: slot = colt(4) x yG(16); colt 3 covers only 2 tiles.
// ---------------------------------------------------------------------------
__global__ __launch_bounds__(256) void gemm_qkv(
    const u16* __restrict__ X3, const u16* __restrict__ W3,
    const float* __restrict__ bq, const float* __restrict__ bk,
    const float* __restrict__ bv,
    u16* __restrict__ Qb, u16* __restrict__ Kb, u16* __restrict__ Vt) {
  const int tid = threadIdx.x;
  const int lane = tid & 63, wid = tid >> 6;
  const int r = lane & 31, h = lane >> 5;
  const int bid = blockIdx.x;
  const int xcd = bid & 7;
  const int slot = bid >> 3;          // 0..63
  const int colt = slot & 3;          // 0..3
  const int yG = slot >> 2;           // 0..15
  const int ytile = yG * 8 + xcd;     // 0..127
  const int m0 = ytile * 128 + wid * 32;
  const int col0 = colt * 128;
  const int NT = (colt == 3) ? 2 : 4; // wave-uniform
  const int mt = m0 >> 5;

  const u16* abase = X3 + (size_t)mt * 10240 + (size_t)h * 256 + r * 8;
  const u16* bbase0 = W3 + (size_t)(colt * 4 + 0) * 10240 + (size_t)h * 256 + r * 8;
  const u16* bbase1 = bbase0 + 10240;
  const u16* bbase2 = bbase0 + 20480;
  const u16* bbase3 = bbase0 + 30720;

  f32x16 acc0 = zero16(), acc1 = zero16(), acc2 = zero16(), acc3 = zero16();
  bf16x8 a  = *(const bf16x8*)(abase);
  bf16x8 b0 = *(const bf16x8*)(bbase0);
  bf16x8 b1 = *(const bf16x8*)(bbase1);
  bf16x8 b2, b3;
  if (NT == 4) {
    b2 = *(const bf16x8*)(bbase2);
    b3 = *(const bf16x8*)(bbase3);
  }
#pragma unroll 1
  for (int ks = 0; ks < 20; ++ks) {
    bf16x8 na, nb0, nb1, nb2, nb3;
    if (ks < 19) {
      na  = *(const bf16x8*)(abase  + (ks + 1) * 512);
      nb0 = *(const bf16x8*)(bbase0 + (ks + 1) * 512);
      nb1 = *(const bf16x8*)(bbase1 + (ks + 1) * 512);
      if (NT == 4) {
        nb2 = *(const bf16x8*)(bbase2 + (ks + 1) * 512);
        nb3 = *(const bf16x8*)(bbase3 + (ks + 1) * 512);
      }
    }
    acc0 = __builtin_amdgcn_mfma_f32_32x32x16_bf16(a, b0, acc0, 0, 0, 0);
    acc1 = __builtin_amdgcn_mfma_f32_32x32x16_bf16(a, b1, acc1, 0, 0, 0);
    if (NT == 4) {
      acc2 = __builtin_amdgcn_mfma_f32_32x32x16_bf16(a, b2, acc2, 0, 0, 0);
      acc3 = __builtin_amdgcn_mfma_f32_32x32x16_bf16(a, b3, acc3, 0, 0, 0);
    }
    a = na; b0 = nb0; b1 = nb1;
    if (NT == 4) { b2 = nb2; b3 = nb3; }
  }

  const int bb = m0 >> 11;        // batch
  const int mloc = m0 & 2047;     // n (or k) within batch

#pragma unroll
  for (int nt = 0; nt < 4; ++nt) {
    if (nt >= NT) continue;
    const int tb = col0 + nt * 32;      // tile base column (uniform)
    const int col = tb + r;
    const f32x16 A = (nt == 0) ? acc0 : (nt == 1) ? acc1 : (nt == 2) ? acc2 : acc3;
    if (tb >= 128) {
      // V3[b][kt8][c][8]
      const int c = col - 128;
      const float bias = bv[c];
      u16* vdst = Vt + (((size_t)(bb * 256 + (mloc >> 3)) * 320 + c) * 8) + 4 * h;
#pragma unroll
      for (int g = 0; g < 4; ++g) {
        us4 o;
#pragma unroll
        for (int e = 0; e < 4; ++e) o[e] = f2b(A[g * 4 + e] + bias);
        *(us4*)(vdst + (size_t)g * 2560) = o;
      }
    } else if (tb >= 64) {
      const float bias = bk[col - 64];
#pragma unroll
      for (int reg = 0; reg < 16; ++reg) {
        const int row = m0 + (reg & 3) + 8 * (reg >> 2) + 4 * h;
        Kb[(size_t)row * CQ + (col - 64)] = f2b(A[reg] + bias);
      }
    } else {
      const float bias = bq[col];
      const int kt = mloc >> 5;
      u16* qdst = Qb + (((size_t)(bb * 64 + kt) * 8 + (col >> 3)) * 32) * 8 + (col & 7);
#pragma unroll
      for (int reg = 0; reg < 16; ++reg) {
        const int kl = (reg & 3) + 8 * (reg >> 2) + 4 * h;
        qdst[kl * 8] = f2b((A[reg] + bias) * LOG2E);
      }
    }
  }
}

// ---------------------------------------------------------------------------
// K3: row sums -> Lb[k] = log2(S[k]). 8 waves (512 thr), grid 256.
// ---------------------------------------------------------------------------
__global__ __launch_bounds__(512) void row_stats(
    const u16* __restrict__ Qb, const u16* __restrict__ Kb,
    float* __restrict__ Lb) {
  __shared__ float Sp[8][64];
  const int tid = threadIdx.x;
  const int lane = tid & 63, wid = tid >> 6;   // 0..7
  const int rl = lane & 15, hq = lane >> 4;
  const int bid = blockIdx.x;
  const int batch = bid & 7;
  const int kloc64 = (bid >> 3) * 64;          // bid>>3 in [0,32)

  bf16x8 af[4][2];
#pragma unroll
  for (int mt = 0; mt < 4; ++mt) {
    const int k_loc = kloc64 + mt * 16 + rl;
    const int kt = k_loc >> 5, kl = k_loc & 31;
#pragma unroll
    for (int qs = 0; qs < 2; ++qs)
      af[mt][qs] = *(const bf16x8*)(Qb +
          (((size_t)(batch * 64 + kt) * 8 + qs * 4 + hq) * 32 + kl) * 8);
  }

  float S[4][4];
#pragma unroll
  for (int mt = 0; mt < 4; ++mt)
#pragma unroll
    for (int rr = 0; rr < 4; ++rr) S[mt][rr] = 0.f;

  const int mstart = batch * NN + wid * 256;
  const u16* kr = Kb + (size_t)(mstart + rl) * CQ + hq * 8;
  bf16x8 c0 = *(const bf16x8*)(kr);
  bf16x8 c1 = *(const bf16x8*)(kr + 32);
#pragma unroll 1
  for (int ms = 0; ms < 16; ++ms) {
    bf16x8 n0, n1;
    if (ms < 15) {
      n0 = *(const bf16x8*)(kr + 16 * CQ);
      n1 = *(const bf16x8*)(kr + 16 * CQ + 32);
    }
#pragma unroll
    for (int mt = 0; mt < 4; ++mt) {
      f32x4 e = zero4();
      e = __builtin_amdgcn_mfma_f32_16x16x32_bf16(af[mt][0], c0, e, 0, 0, 0);
      e = __builtin_amdgcn_mfma_f32_16x16x32_bf16(af[mt][1], c1, e, 0, 0, 0);
#pragma unroll
      for (int rr = 0; rr < 4; ++rr) S[mt][rr] += __builtin_amdgcn_exp2f(e[rr]);
    }
    c0 = n0; c1 = n1; kr += 16 * CQ;
  }

#pragma unroll
  for (int d = 1; d < 16; d <<= 1)
#pragma unroll
    for (int mt = 0; mt < 4; ++mt)
#pragma unroll
      for (int rr = 0; rr < 4; ++rr) S[mt][rr] += __shfl_xor(S[mt][rr], d, 64);

  if (rl == 0) {
#pragma unroll
    for (int mt = 0; mt < 4; ++mt)
#pragma unroll
      for (int rr = 0; rr < 4; ++rr) Sp[wid][mt * 16 + hq * 4 + rr] = S[mt][rr];
  }
  __syncthreads();
  if (tid < 64) {
    float s = 0.f;
#pragma unroll
    for (int p = 0; p < 8; ++p) s += Sp[p][tid];
    Lb[batch * NN + kloc64 + tid] = __log2f(s);
  }
}

// ---------------------------------------------------------------------------
// K4: attention v14 — 64k tiles (2 x 32k sub-tiles per barrier interval),
// DYNAMIC LDS 81920 B (r16's design failed only because static __shared__
// >64KB silently fails to launch; dynamic LDS supports it, cf. m201 128KB).
// 16 barrier intervals instead of 32. Same double-buffer discipline as the
// passing r14/r15/r17 kernels: STAGE(next)->COMPUTE(cur)->barrier.
// L from global (r17 showed LDS-L neutral). setprio around PV (r18, +6%).
// Block = 256 thr = 4 waves: (wn n-tile 0/1) x (kh k-half 0/1).
// Grid 512 = 8b x 2ch x 32 n-pairs; batch = bid&7 (XCD-pinned).
// ---------------------------------------------------------------------------
__global__ __launch_bounds__(256, 2) void attn(
    const u16* __restrict__ Qb, const u16* __restrict__ Kb,
    const u16* __restrict__ Vt, const float* __restrict__ Lb,
    const float* __restrict__ x, const float* __restrict__ gamma,
    float* __restrict__ out) {
  extern __shared__ __align__(16) char LDSRAW[];   // 2 bufs x 40960 (64k tile)
  const int tid = threadIdx.x;
  const int lane = tid & 63, wid = tid >> 6;
  const int wn = wid >> 1;       // n-tile within pair
  const int kh = wid & 1;        // k-half
  const int r = lane & 31, h = lane >> 5;
  const int bid = blockIdx.x;
  const int b = bid & 7;
  const int rest = bid >> 3;
  const int ch = rest & 1;
  const int n0 = (rest >> 1) * 64;

  // K fragments for n-tile n0 + wn*32 (held all k)
  bf16x8 kf[4];
  {
    const u16* krow = Kb + (size_t)(b * NN + n0 + wn * 32 + r) * CQ + h * 8;
#pragma unroll
    for (int qs = 0; qs < 4; ++qs) kf[qs] = *(const bf16x8*)(krow + qs * 16);
  }

  f32x16 acc[5];
#pragma unroll
  for (int j = 0; j < 5; ++j) acc[j] = zero16();

  // per-wave bases for this k-half
  const u16* qb3 = Qb + ((size_t)(b * 64 + kh * 32) * 8) * 256 + (size_t)r * 8;
  const float* lbase = Lb + b * NN + kh * 1024 + 4 * h;

  // stage V for 64k tile TN: 40 chunks of 1KB (20 per kh), wave: 10 chunks
#define STAGE64(TN, BUF) {                                                     \
    _Pragma("unroll")                                                          \
    for (int i_ = 0; i_ < 10; ++i_) {                                          \
      const int c_ = wid * 10 + i_;                                            \
      const int khc_ = c_ / 20;                                                \
      const int rem_ = c_ % 20;                                                \
      char* dst_ = LDSRAW + (BUF) * 40960 + khc_ * 20480 + rem_ * 1024;        \
      const int off_ = rem_ * 512 + lane * 8;                                  \
      const int row_ = off_ / 1280;                                            \
      const int win_ = off_ - row_ * 1280;                                     \
      const u16* src_ = Vt +                                                   \
          ((size_t)(b * 256 + khc_ * 128 + (TN) * 8 + row_) * 320              \
           + ch * 160) * 8 + win_;                                             \
      gll16(src_, dst_);                                                       \
    }                                                                          \
  }

// prefetch Q frags for 32k sub-tile index KT32 into QN
#define LQ(QN, KT32) {                                                         \
    _Pragma("unroll")                                                          \
    for (int qs = 0; qs < 4; ++qs)                                             \
      QN[qs] = *(const bf16x8*)(qb3 + ((size_t)(KT32) * 8 + qs * 2 + h) * 256);\
  }

// compute 32k sub-tile KT32 from buffer BUF at sub-offset SOFF using QF
#define COMPUTE32(KT32, BUF, SOFF, QF) {                                       \
    float4 LF0 = *(const float4*)(lbase + (KT32) * 32);                        \
    float4 LF1 = *(const float4*)(lbase + (KT32) * 32 + 8);                    \
    float4 LF2 = *(const float4*)(lbase + (KT32) * 32 + 16);                   \
    float4 LF3 = *(const float4*)(lbase + (KT32) * 32 + 24);                   \
    const char* base_ = LDSRAW + (BUF) * 40960 + kh * 20480 + (SOFF);          \
    f32x16 e = zero16();                                                       \
    _Pragma("unroll")                                                          \
    for (int qs = 0; qs < 4; ++qs)                                             \
      e = __builtin_amdgcn_mfma_f32_32x32x16_bf16(QF[qs], kf[qs], e, 0, 0, 0); \
    bf16x8 vf[5][2];                                                           \
    _Pragma("unroll")                                                          \
    for (int j = 0; j < 5; ++j)                                                \
      _Pragma("unroll")                                                        \
      for (int ks = 0; ks < 2; ++ks)                                           \
        vf[j][ks] = *(const bf16x8*)(base_ + (ks * 2 + h) * 2560               \
                                     + (j * 32 + r) * 16);                     \
    unsigned pk0, pk1, pk2, pk3, pk4, pk5, pk6, pk7;                           \
    { float l0 = __builtin_amdgcn_exp2f(e[0]  - LF0.x);                        \
      float h0 = __builtin_amdgcn_exp2f(e[1]  - LF0.y);                        \
      float l1 = __builtin_amdgcn_exp2f(e[2]  - LF0.z);                        \
      float h1 = __builtin_amdgcn_exp2f(e[3]  - LF0.w);                        \
      float l2 = __builtin_amdgcn_exp2f(e[4]  - LF1.x);                        \
      float h2 = __builtin_amdgcn_exp2f(e[5]  - LF1.y);                        \
      float l3 = __builtin_amdgcn_exp2f(e[6]  - LF1.z);                        \
      float h3 = __builtin_amdgcn_exp2f(e[7]  - LF1.w);                        \
      float l4 = __builtin_amdgcn_exp2f(e[8]  - LF2.x);                        \
      float h4 = __builtin_amdgcn_exp2f(e[9]  - LF2.y);                        \
      float l5 = __builtin_amdgcn_exp2f(e[10] - LF2.z);                        \
      float h5 = __builtin_amdgcn_exp2f(e[11] - LF2.w);                        \
      float l6 = __builtin_amdgcn_exp2f(e[12] - LF3.x);                        \
      float h6 = __builtin_amdgcn_exp2f(e[13] - LF3.y);                        \
      float l7 = __builtin_amdgcn_exp2f(e[14] - LF3.z);                        \
      float h7 = __builtin_amdgcn_exp2f(e[15] - LF3.w);                        \
      asm("v_cvt_pk_bf16_f32 %0, %1, %2" : "=v"(pk0) : "v"(l0), "v"(h0));      \
      asm("v_cvt_pk_bf16_f32 %0, %1, %2" : "=v"(pk1) : "v"(l1), "v"(h1));      \
      asm("v_cvt_pk_bf16_f32 %0, %1, %2" : "=v"(pk2) : "v"(l2), "v"(h2));      \
      asm("v_cvt_pk_bf16_f32 %0, %1, %2" : "=v"(pk3) : "v"(l3), "v"(h3));      \
      asm("v_cvt_pk_bf16_f32 %0, %1, %2" : "=v"(pk4) : "v"(l4), "v"(h4));      \
      asm("v_cvt_pk_bf16_f32 %0, %1, %2" : "=v"(pk5) : "v"(l5), "v"(h5));      \
      asm("v_cvt_pk_bf16_f32 %0, %1, %2" : "=v"(pk6) : "v"(l6), "v"(h6));      \
      asm("v_cvt_pk_bf16_f32 %0, %1, %2" : "=v"(pk7) : "v"(l7), "v"(h7)); }    \
    asm("v_permlane32_swap_b32 %0, %1" : "+v"(pk0), "+v"(pk2));                \
    asm("v_permlane32_swap_b32 %0, %1" : "+v"(pk1), "+v"(pk3));                \
    asm("v_permlane32_swap_b32 %0, %1" : "+v"(pk4), "+v"(pk6));                \
    asm("v_permlane32_swap_b32 %0, %1" : "+v"(pk5), "+v"(pk7));                \
    u32x4 w0_ = {pk0, pk1, pk2, pk3};                                          \
    u32x4 w1_ = {pk4, pk5, pk6, pk7};                                          \
    bf16x8 pa0 = __builtin_bit_cast(bf16x8, w0_);                              \
    bf16x8 pa1 = __builtin_bit_cast(bf16x8, w1_);                              \
    __builtin_amdgcn_s_setprio(1);                                             \
    _Pragma("unroll")                                                          \
    for (int j = 0; j < 5; ++j) {                                              \
      acc[j] = __builtin_amdgcn_mfma_f32_32x32x16_bf16(pa0, vf[j][0], acc[j], 0, 0, 0); \
      acc[j] = __builtin_amdgcn_mfma_f32_32x32x16_bf16(pa1, vf[j][1], acc[j], 0, 0, 0); \
    }                                                                          \
    __builtin_amdgcn_s_setprio(0);                                             \
  }

  bf16x8 qfA[4], qfB[4], qfs1[4];

  STAGE64(0, 0);
  LQ(qfA, 0)
  __syncthreads();
#pragma unroll 1
  for (int t = 0; t < 16; t += 2) {
    STAGE64(t + 1, 1);                   // next 64k tile -> buf1
    LQ(qfB, (t + 1) * 2)                 // next tile sub0 (cross-barrier)
    LQ(qfs1, t * 2 + 1)                  // this tile sub1 (used below)
    COMPUTE32(t * 2,     0, 0,     qfA); // tile t sub0
    COMPUTE32(t * 2 + 1, 0, 10240, qfs1);// tile t sub1
    __syncthreads();
    if (t + 2 < 16) STAGE64(t + 2, 0);
    LQ(qfA, ((t + 2) & 15) * 2)
    LQ(qfs1, (t + 1) * 2 + 1)
    COMPUTE32((t + 1) * 2,     1, 0,     qfB);
    COMPUTE32((t + 1) * 2 + 1, 1, 10240, qfs1);
    __syncthreads();
  }
#undef STAGE64
#undef LQ
#undef COMPUTE32

  // kh=1 waves dump partial sums; kh=0 waves combine and write out
  float* red = (float*)LDSRAW;   // 2 regions x 5120 f32 = 40960 B (fits)
  if (kh == 1) {
#pragma unroll
    for (int reg = 0; reg < 16; ++reg) {
      const int nl = (reg & 3) + 8 * (reg >> 2) + 4 * h;
#pragma unroll
      for (int j = 0; j < 5; ++j)
        red[wn * 5120 + nl * 160 + j * 32 + r] = acc[j][reg];
    }
  }
  __syncthreads();
  if (kh == 0) {
    const float g = gamma[0];
#pragma unroll
    for (int reg = 0; reg < 16; ++reg) {
      const int nl = (reg & 3) + 8 * (reg >> 2) + 4 * h;
      const size_t rowb = ((size_t)(b * NN) + n0 + wn * 32 + nl) * CC + ch * 160 + r;
#pragma unroll
      for (int j = 0; j < 5; ++j) {
        const size_t idx = rowb + (size_t)(j * 32);
        const float s = acc[j][reg] + red[wn * 5120 + nl * 160 + j * 32 + r];
        out[idx] = g * s + x[idx];
      }
    }
  }
}

extern "C" void kernel_launch(void* const* d_in, const int* in_sizes, int n_in,
                              void* d_out, int out_size, void* d_ws, size_t ws_size,
                              hipStream_t stream) {
  const float* x     = (const float*)d_in[0];
  const float* Wq    = (const float*)d_in[1];
  const float* bq    = (const float*)d_in[2];
  const float* Wk    = (const float*)d_in[3];
  const float* bk    = (const float*)d_in[4];
  const float* Wv    = (const float*)d_in[5];
  const float* bv    = (const float*)d_in[6];
  const float* gamma = (const float*)d_in[7];
  float* out = (float*)d_out;

  char* w = (char*)d_ws;
  u16* X3   = (u16*)(w);                       // 512*40*32*8 (10485760 B)
  u16* W3   = (u16*)(w + 10485760);            // 14*40*32*8  (286720 B)
  u16* Qb   = (u16*)(w + 10772480);            // Q3: 8*64*8*32*8 (2097152 B)
  u16* Kb   = (u16*)(w + 12869632);            // 16384*64    (2097152 B)
  u16* Vt   = (u16*)(w + 14966784);            // V3: 8*256*320*8 (10485760 B)
  float* Lb = (float*)(w + 25452544);          // 16384 f32   (65536 B)

  cvt_blk<<<526, 256, 0, stream>>>(x, Wq, Wk, Wv, X3, W3);
  gemm_qkv<<<512, 256, 0, stream>>>(X3, W3, bq, bk, bv, Qb, Kb, Vt);
  row_stats<<<256, 512, 0, stream>>>(Qb, Kb, Lb);
  attn<<<512, 256, 81920, stream>>>(Qb, Kb, Vt, Lb, x, gamma, out);
}

// Round 20
// 77.750 us; speedup vs baseline: 1.2613x; 1.2613x over previous
//
#include <hip/hip_runtime.h>
#include <hip/hip_bf16.h>

#define BB 8
#define NN 2048
#define CC 320
#define CQ 64
#define LOG2E 1.4426950408889634f

typedef __attribute__((ext_vector_type(8)))  short bf16x8;
typedef __attribute__((ext_vector_type(4)))  float f32x4;
typedef __attribute__((ext_vector_type(16))) float f32x16;
typedef __attribute__((ext_vector_type(4)))  unsigned short us4;
typedef __attribute__((ext_vector_type(8)))  unsigned short us8;
typedef __attribute__((ext_vector_type(4)))  unsigned int u32x4;
typedef unsigned short u16;

// Layouts:
//  X3[mt=m/32][kk8=k/8][ml=m%32][8]       (bf16; lane-contiguous A-frags)
//  W3[ct=c/32][kk8=k/8][cl=c%32][8]       (bf16; lane-contiguous B-frags)
//  Q3[b][kt=k/32][cq8=cq/8][kl=k%32][8]   (bf16, pre-scaled by log2e)
//  Kb[b*N+n][cq]                          (row-major)
//  V3[b][kt8=k/8][c][8]                   (bf16, UNSCALED — read-only)
//  Lb[b*N+k]                              (f32, log2 of softmax row sum)

static __device__ __forceinline__ u16 f2b(float f) {
  unsigned u = __builtin_bit_cast(unsigned, f);
  unsigned r = (u + 0x7FFFu + ((u >> 16) & 1u)) >> 16;
  return (u16)r;
}
static __device__ __forceinline__ float b2f(u16 s) {
  unsigned u = ((unsigned)s) << 16;
  return __builtin_bit_cast(float, u);
}

static __device__ __forceinline__ f32x16 zero16() {
  f32x16 v = {0,0,0,0, 0,0,0,0, 0,0,0,0, 0,0,0,0};
  return v;
}
static __device__ __forceinline__ f32x4 zero4() {
  f32x4 v = {0,0,0,0};
  return v;
}

static __device__ __forceinline__ void gll16(const void* g, void* l) {
  __builtin_amdgcn_global_load_lds(
      (const __attribute__((address_space(1))) unsigned int*)g,
      (__attribute__((address_space(3))) unsigned int*)l, 16, 0, 0);
}

// 8 fp32 -> bf16x8 via hardware packed converts (RNE, same as f2b)
static __device__ __forceinline__ bf16x8 cvt8(float4 a, float4 b) {
  unsigned p0, p1, p2, p3;
  asm("v_cvt_pk_bf16_f32 %0, %1, %2" : "=v"(p0) : "v"(a.x), "v"(a.y));
  asm("v_cvt_pk_bf16_f32 %0, %1, %2" : "=v"(p1) : "v"(a.z), "v"(a.w));
  asm("v_cvt_pk_bf16_f32 %0, %1, %2" : "=v"(p2) : "v"(b.x), "v"(b.y));
  asm("v_cvt_pk_bf16_f32 %0, %1, %2" : "=v"(p3) : "v"(b.z), "v"(b.w));
  u32x4 w = {p0, p1, p2, p3};
  return __builtin_bit_cast(bf16x8, w);
}

// ---------------------------------------------------------------------------
// K0: fused conversion. blocks 0..511: x -> X3; blocks 512..525: W -> W3.
// grid 526 x 256.
// ---------------------------------------------------------------------------
__global__ __launch_bounds__(256) void cvt_blk(const float* __restrict__ x,
                                               const float* __restrict__ Wq,
                                               const float* __restrict__ Wk,
                                               const float* __restrict__ Wv,
                                               u16* __restrict__ X3,
                                               u16* __restrict__ W3) {
  __shared__ float xs[32][324];   // +4 pad: conflict-free transpose reads
  const int t = threadIdx.x;
  const int bid = blockIdx.x;
  const bool isX = (bid < 512);
  const int b = isX ? bid : (bid - 512);
#pragma unroll
  for (int i = 0; i < 10; ++i) {
    const int lidx = i * 256 + t;        // 0..2559 float4 units
    const int m = lidx / 80;             // 80 float4 per row
    const int kq = lidx - m * 80;
    const float* src;
    if (isX) {
      src = x + (size_t)(b * 32 + m) * CC;
    } else {
      const int row = b * 32 + m;
      src = (row < 64) ? (Wq + (size_t)row * CC)
          : (row < 128) ? (Wk + (size_t)(row - 64) * CC)
                        : (Wv + (size_t)(row - 128) * CC);
    }
    float4 v = *(const float4*)(src + kq * 4);
    *(float4*)&xs[m][kq * 4] = v;
  }
  __syncthreads();
  u16* dst0 = (isX ? X3 : W3) + (size_t)b * 10240;
#pragma unroll
  for (int i = 0; i < 5; ++i) {
    const int u = i * 256 + t;           // 0..1279: kk8*32 + ml
    const int kk8 = u >> 5, ml = u & 31;
    float4 a = *(const float4*)&xs[ml][kk8 * 8];
    float4 c = *(const float4*)&xs[ml][kk8 * 8 + 4];
    bf16x8 o = cvt8(a, c);
    *(bf16x8*)(dst0 + (size_t)u * 8) = o;
  }
}

// ---------------------------------------------------------------------------
// K1: QKV GEMM, wide 128-col wave tiles (4 MFMA per 5 loads). XCD remap.
// grid 512 x 256: slot = colt(4) x yG(16); colt 3 covers only 2 tiles.
// ---------------------------------------------------------------------------
__global__ __launch_bounds__(256) void gemm_qkv(
    const u16* __restrict__ X3, const u16* __restrict__ W3,
    const float* __restrict__ bq, const float* __restrict__ bk,
    const float* __restrict__ bv,
    u16* __restrict__ Qb, u16* __restrict__ Kb, u16* __restrict__ Vt) {
  const int tid = threadIdx.x;
  const int lane = tid & 63, wid = tid >> 6;
  const int r = lane & 31, h = lane >> 5;
  const int bid = blockIdx.x;
  const int xcd = bid & 7;
  const int slot = bid >> 3;          // 0..63
  const int colt = slot & 3;          // 0..3
  const int yG = slot >> 2;           // 0..15
  const int ytile = yG * 8 + xcd;     // 0..127
  const int m0 = ytile * 128 + wid * 32;
  const int col0 = colt * 128;
  const int NT = (colt == 3) ? 2 : 4; // wave-uniform
  const int mt = m0 >> 5;

  const u16* abase = X3 + (size_t)mt * 10240 + (size_t)h * 256 + r * 8;
  const u16* bbase0 = W3 + (size_t)(colt * 4 + 0) * 10240 + (size_t)h * 256 + r * 8;
  const u16* bbase1 = bbase0 + 10240;
  const u16* bbase2 = bbase0 + 20480;
  const u16* bbase3 = bbase0 + 30720;

  f32x16 acc0 = zero16(), acc1 = zero16(), acc2 = zero16(), acc3 = zero16();
  bf16x8 a  = *(const bf16x8*)(abase);
  bf16x8 b0 = *(const bf16x8*)(bbase0);
  bf16x8 b1 = *(const bf16x8*)(bbase1);
  bf16x8 b2, b3;
  if (NT == 4) {
    b2 = *(const bf16x8*)(bbase2);
    b3 = *(const bf16x8*)(bbase3);
  }
#pragma unroll 1
  for (int ks = 0; ks < 20; ++ks) {
    bf16x8 na, nb0, nb1, nb2, nb3;
    if (ks < 19) {
      na  = *(const bf16x8*)(abase  + (ks + 1) * 512);
      nb0 = *(const bf16x8*)(bbase0 + (ks + 1) * 512);
      nb1 = *(const bf16x8*)(bbase1 + (ks + 1) * 512);
      if (NT == 4) {
        nb2 = *(const bf16x8*)(bbase2 + (ks + 1) * 512);
        nb3 = *(const bf16x8*)(bbase3 + (ks + 1) * 512);
      }
    }
    acc0 = __builtin_amdgcn_mfma_f32_32x32x16_bf16(a, b0, acc0, 0, 0, 0);
    acc1 = __builtin_amdgcn_mfma_f32_32x32x16_bf16(a, b1, acc1, 0, 0, 0);
    if (NT == 4) {
      acc2 = __builtin_amdgcn_mfma_f32_32x32x16_bf16(a, b2, acc2, 0, 0, 0);
      acc3 = __builtin_amdgcn_mfma_f32_32x32x16_bf16(a, b3, acc3, 0, 0, 0);
    }
    a = na; b0 = nb0; b1 = nb1;
    if (NT == 4) { b2 = nb2; b3 = nb3; }
  }

  const int bb = m0 >> 11;        // batch
  const int mloc = m0 & 2047;     // n (or k) within batch

#pragma unroll
  for (int nt = 0; nt < 4; ++nt) {
    if (nt >= NT) continue;
    const int tb = col0 + nt * 32;      // tile base column (uniform)
    const int col = tb + r;
    const f32x16 A = (nt == 0) ? acc0 : (nt == 1) ? acc1 : (nt == 2) ? acc2 : acc3;
    if (tb >= 128) {
      // V3[b][kt8][c][8]
      const int c = col - 128;
      const float bias = bv[c];
      u16* vdst = Vt + (((size_t)(bb * 256 + (mloc >> 3)) * 320 + c) * 8) + 4 * h;
#pragma unroll
      for (int g = 0; g < 4; ++g) {
        us4 o;
#pragma unroll
        for (int e = 0; e < 4; ++e) o[e] = f2b(A[g * 4 + e] + bias);
        *(us4*)(vdst + (size_t)g * 2560) = o;
      }
    } else if (tb >= 64) {
      const float bias = bk[col - 64];
#pragma unroll
      for (int reg = 0; reg < 16; ++reg) {
        const int row = m0 + (reg & 3) + 8 * (reg >> 2) + 4 * h;
        Kb[(size_t)row * CQ + (col - 64)] = f2b(A[reg] + bias);
      }
    } else {
      const float bias = bq[col];
      const int kt = mloc >> 5;
      u16* qdst = Qb + (((size_t)(bb * 64 + kt) * 8 + (col >> 3)) * 32) * 8 + (col & 7);
#pragma unroll
      for (int reg = 0; reg < 16; ++reg) {
        const int kl = (reg & 3) + 8 * (reg >> 2) + 4 * h;
        qdst[kl * 8] = f2b((A[reg] + bias) * LOG2E);
      }
    }
  }
}

// ---------------------------------------------------------------------------
// K3: row sums -> Lb[k] = log2(S[k]). 8 waves (512 thr), grid 256.
// ---------------------------------------------------------------------------
__global__ __launch_bounds__(512) void row_stats(
    const u16* __restrict__ Qb, const u16* __restrict__ Kb,
    float* __restrict__ Lb) {
  __shared__ float Sp[8][64];
  const int tid = threadIdx.x;
  const int lane = tid & 63, wid = tid >> 6;   // 0..7
  const int rl = lane & 15, hq = lane >> 4;
  const int bid = blockIdx.x;
  const int batch = bid & 7;
  const int kloc64 = (bid >> 3) * 64;          // bid>>3 in [0,32)

  bf16x8 af[4][2];
#pragma unroll
  for (int mt = 0; mt < 4; ++mt) {
    const int k_loc = kloc64 + mt * 16 + rl;
    const int kt = k_loc >> 5, kl = k_loc & 31;
#pragma unroll
    for (int qs = 0; qs < 2; ++qs)
      af[mt][qs] = *(const bf16x8*)(Qb +
          (((size_t)(batch * 64 + kt) * 8 + qs * 4 + hq) * 32 + kl) * 8);
  }

  float S[4][4];
#pragma unroll
  for (int mt = 0; mt < 4; ++mt)
#pragma unroll
    for (int rr = 0; rr < 4; ++rr) S[mt][rr] = 0.f;

  const int mstart = batch * NN + wid * 256;
  const u16* kr = Kb + (size_t)(mstart + rl) * CQ + hq * 8;
  bf16x8 c0 = *(const bf16x8*)(kr);
  bf16x8 c1 = *(const bf16x8*)(kr + 32);
#pragma unroll 1
  for (int ms = 0; ms < 16; ++ms) {
    bf16x8 n0, n1;
    if (ms < 15) {
      n0 = *(const bf16x8*)(kr + 16 * CQ);
      n1 = *(const bf16x8*)(kr + 16 * CQ + 32);
    }
#pragma unroll
    for (int mt = 0; mt < 4; ++mt) {
      f32x4 e = zero4();
      e = __builtin_amdgcn_mfma_f32_16x16x32_bf16(af[mt][0], c0, e, 0, 0, 0);
      e = __builtin_amdgcn_mfma_f32_16x16x32_bf16(af[mt][1], c1, e, 0, 0, 0);
#pragma unroll
      for (int rr = 0; rr < 4; ++rr) S[mt][rr] += __builtin_amdgcn_exp2f(e[rr]);
    }
    c0 = n0; c1 = n1; kr += 16 * CQ;
  }

#pragma unroll
  for (int d = 1; d < 16; d <<= 1)
#pragma unroll
    for (int mt = 0; mt < 4; ++mt)
#pragma unroll
      for (int rr = 0; rr < 4; ++rr) S[mt][rr] += __shfl_xor(S[mt][rr], d, 64);

  if (rl == 0) {
#pragma unroll
    for (int mt = 0; mt < 4; ++mt)
#pragma unroll
      for (int rr = 0; rr < 4; ++rr) Sp[wid][mt * 16 + hq * 4 + rr] = S[mt][rr];
  }
  __syncthreads();
  if (tid < 64) {
    float s = 0.f;
#pragma unroll
    for (int p = 0; p < 8; ++p) s += Sp[p][tid];
    Lb[batch * NN + kloc64 + tid] = __log2f(s);
  }
}

// ---------------------------------------------------------------------------
// K4: attention v13 (r18-passing) — V-only LDS staging (40 KB dbuf) + 8 KB
// L stage; Q register-prefetched one tile ahead (named A/B); setprio around
// PV MFMA cluster. Skeleton: STAGE(t+1) -> COMPUTE(t) -> barrier.
// Block = 256 thr = 4 waves: (wn n-tile 0/1) x (kh k-half 0/1).
// Grid 512 = 8b x 2ch x 32 n-pairs; batch = bid&7 (XCD-pinned).
// ---------------------------------------------------------------------------
__global__ __launch_bounds__(256, 2) void attn(
    const u16* __restrict__ Qb, const u16* __restrict__ Kb,
    const u16* __restrict__ Vt, const float* __restrict__ Lb,
    const float* __restrict__ x, const float* __restrict__ gamma,
    float* __restrict__ out) {
  __shared__ __align__(16) char LDSRAW[49152];   // 40KB V bufs + 8KB L
  float* Ls = (float*)(LDSRAW + 40960);          // [2048] = both kh halves
  const int tid = threadIdx.x;
  const int lane = tid & 63, wid = tid >> 6;
  const int wn = wid >> 1;       // n-tile within pair
  const int kh = wid & 1;        // k-half
  const int r = lane & 31, h = lane >> 5;
  const int bid = blockIdx.x;
  const int b = bid & 7;
  const int rest = bid >> 3;
  const int ch = rest & 1;
  const int n0 = (rest >> 1) * 64;

  // one-time: stage this batch's L (2048 f32, 8 KB) into LDS
#pragma unroll
  for (int i = 0; i < 8; ++i)
    Ls[i * 256 + tid] = Lb[b * NN + i * 256 + tid];

  // K fragments for n-tile n0 + wn*32 (held all k)
  bf16x8 kf[4];
  {
    const u16* krow = Kb + (size_t)(b * NN + n0 + wn * 32 + r) * CQ + h * 8;
#pragma unroll
    for (int qs = 0; qs < 4; ++qs) kf[qs] = *(const bf16x8*)(krow + qs * 16);
  }

  f32x16 acc[5];
#pragma unroll
  for (int j = 0; j < 5; ++j) acc[j] = zero16();

  // per-wave bases for this k-half
  const u16* qb3 = Qb + ((size_t)(b * 64 + kh * 32) * 8) * 256 + (size_t)r * 8;
  const float* lsb = Ls + kh * 1024 + 4 * h;   // LDS pointer (per-lane via h)

  // stage V only: 20 chunks of 1KB (10 per kh), wave w takes [w*5, w*5+5)
#define STAGE(TN, BUF) {                                                       \
    _Pragma("unroll")                                                          \
    for (int i_ = 0; i_ < 5; ++i_) {                                           \
      const int c_ = wid * 5 + i_;                                             \
      const int khc_ = c_ / 10;                                                \
      const int rem_ = c_ % 10;                                                \
      char* dst_ = LDSRAW + (BUF) * 20480 + khc_ * 10240 + rem_ * 1024;        \
      const int off_ = rem_ * 512 + lane * 8;                                  \
      const int row_ = off_ / 1280;                                            \
      const int win_ = off_ - row_ * 1280;                                     \
      const u16* src_ = Vt +                                                   \
          ((size_t)(b * 256 + khc_ * 128 + (TN) * 4 + row_) * 320              \
           + ch * 160) * 8 + win_;                                             \
      gll16(src_, dst_);                                                       \
    }                                                                          \
  }

// prefetch Q frags for tile TN into QN (plain global loads, lane-contiguous)
#define LQ(QN, TN) {                                                           \
    _Pragma("unroll")                                                          \
    for (int qs = 0; qs < 4; ++qs)                                             \
      QN[qs] = *(const bf16x8*)(qb3 + ((size_t)(TN) * 8 + qs * 2 + h) * 256);  \
  }

// compute tile T from LDS buffer BUF using prefetched QF; prefetch QN (TNX);
// L read from LDS (broadcast ds_read, lgkm queue)
#define COMPUTE(T, BUF, QF, QN, TNX) {                                         \
    LQ(QN, TNX)                                                                \
    float4 LF0 = *(const float4*)(lsb + (T) * 32);                             \
    float4 LF1 = *(const float4*)(lsb + (T) * 32 + 8);                         \
    float4 LF2 = *(const float4*)(lsb + (T) * 32 + 16);                        \
    float4 LF3 = *(const float4*)(lsb + (T) * 32 + 24);                        \
    const char* base_ = LDSRAW + (BUF) * 20480 + kh * 10240;                   \
    f32x16 e = zero16();                                                       \
    _Pragma("unroll")                                                          \
    for (int qs = 0; qs < 4; ++qs)                                             \
      e = __builtin_amdgcn_mfma_f32_32x32x16_bf16(QF[qs], kf[qs], e, 0, 0, 0); \
    bf16x8 vf[5][2];                                                           \
    _Pragma("unroll")                                                          \
    for (int j = 0; j < 5; ++j)                                                \
      _Pragma("unroll")                                                        \
      for (int ks = 0; ks < 2; ++ks)                                           \
        vf[j][ks] = *(const bf16x8*)(base_ + (ks * 2 + h) * 2560               \
                                     + (j * 32 + r) * 16);                     \
    unsigned pk0, pk1, pk2, pk3, pk4, pk5, pk6, pk7;                           \
    { float l0 = __builtin_amdgcn_exp2f(e[0]  - LF0.x);                        \
      float h0 = __builtin_amdgcn_exp2f(e[1]  - LF0.y);                        \
      float l1 = __builtin_amdgcn_exp2f(e[2]  - LF0.z);                        \
      float h1 = __builtin_amdgcn_exp2f(e[3]  - LF0.w);                        \
      float l2 = __builtin_amdgcn_exp2f(e[4]  - LF1.x);                        \
      float h2 = __builtin_amdgcn_exp2f(e[5]  - LF1.y);                        \
      float l3 = __builtin_amdgcn_exp2f(e[6]  - LF1.z);                        \
      float h3 = __builtin_amdgcn_exp2f(e[7]  - LF1.w);                        \
      float l4 = __builtin_amdgcn_exp2f(e[8]  - LF2.x);                        \
      float h4 = __builtin_amdgcn_exp2f(e[9]  - LF2.y);                        \
      float l5 = __builtin_amdgcn_exp2f(e[10] - LF2.z);                        \
      float h5 = __builtin_amdgcn_exp2f(e[11] - LF2.w);                        \
      float l6 = __builtin_amdgcn_exp2f(e[12] - LF3.x);                        \
      float h6 = __builtin_amdgcn_exp2f(e[13] - LF3.y);                        \
      float l7 = __builtin_amdgcn_exp2f(e[14] - LF3.z);                        \
      float h7 = __builtin_amdgcn_exp2f(e[15] - LF3.w);                        \
      asm("v_cvt_pk_bf16_f32 %0, %1, %2" : "=v"(pk0) : "v"(l0), "v"(h0));      \
      asm("v_cvt_pk_bf16_f32 %0, %1, %2" : "=v"(pk1) : "v"(l1), "v"(h1));      \
      asm("v_cvt_pk_bf16_f32 %0, %1, %2" : "=v"(pk2) : "v"(l2), "v"(h2));      \
      asm("v_cvt_pk_bf16_f32 %0, %1, %2" : "=v"(pk3) : "v"(l3), "v"(h3));      \
      asm("v_cvt_pk_bf16_f32 %0, %1, %2" : "=v"(pk4) : "v"(l4), "v"(h4));      \
      asm("v_cvt_pk_bf16_f32 %0, %1, %2" : "=v"(pk5) : "v"(l5), "v"(h5));      \
      asm("v_cvt_pk_bf16_f32 %0, %1, %2" : "=v"(pk6) : "v"(l6), "v"(h6));      \
      asm("v_cvt_pk_bf16_f32 %0, %1, %2" : "=v"(pk7) : "v"(l7), "v"(h7)); }    \
    asm("v_permlane32_swap_b32 %0, %1" : "+v"(pk0), "+v"(pk2));                \
    asm("v_permlane32_swap_b32 %0, %1" : "+v"(pk1), "+v"(pk3));                \
    asm("v_permlane32_swap_b32 %0, %1" : "+v"(pk4), "+v"(pk6));                \
    asm("v_permlane32_swap_b32 %0, %1" : "+v"(pk5), "+v"(pk7));                \
    u32x4 w0_ = {pk0, pk1, pk2, pk3};                                          \
    u32x4 w1_ = {pk4, pk5, pk6, pk7};                                          \
    bf16x8 pa0 = __builtin_bit_cast(bf16x8, w0_);                              \
    bf16x8 pa1 = __builtin_bit_cast(bf16x8, w1_);                              \
    __builtin_amdgcn_s_setprio(1);                                             \
    _Pragma("unroll")                                                          \
    for (int j = 0; j < 5; ++j) {                                              \
      acc[j] = __builtin_amdgcn_mfma_f32_32x32x16_bf16(pa0, vf[j][0], acc[j], 0, 0, 0); \
      acc[j] = __builtin_amdgcn_mfma_f32_32x32x16_bf16(pa1, vf[j][1], acc[j], 0, 0, 0); \
    }                                                                          \
    __builtin_amdgcn_s_setprio(0);                                             \
  }

  bf16x8 qfA[4], qfB[4];

  STAGE(0, 0);
  LQ(qfA, 0)
  __syncthreads();                 // V tile 0 staged + Ls filled (all waves)
#pragma unroll 1
  for (int t = 0; t < 32; t += 2) {
    STAGE(t + 1, 1);                          // odd tile -> buf1
    COMPUTE(t, 0, qfA, qfB, t + 1);           // even tile from buf0
    __syncthreads();
    if (t + 2 < 32) STAGE(t + 2, 0);          // even tile -> buf0
    COMPUTE(t + 1, 1, qfB, qfA, (t + 2) & 31);// odd tile from buf1
    __syncthreads();
  }
#undef STAGE
#undef LQ
#undef COMPUTE

  // kh=1 waves dump partial sums; kh=0 waves combine and write out
  float* red = (float*)LDSRAW;   // 2 regions x 5120 f32 = 40960 B (fits)
  if (kh == 1) {
#pragma unroll
    for (int reg = 0; reg < 16; ++reg) {
      const int nl = (reg & 3) + 8 * (reg >> 2) + 4 * h;
#pragma unroll
      for (int j = 0; j < 5; ++j)
        red[wn * 5120 + nl * 160 + j * 32 + r] = acc[j][reg];
    }
  }
  __syncthreads();
  if (kh == 0) {
    const float g = gamma[0];
#pragma unroll
    for (int reg = 0; reg < 16; ++reg) {
      const int nl = (reg & 3) + 8 * (reg >> 2) + 4 * h;
      const size_t rowb = ((size_t)(b * NN) + n0 + wn * 32 + nl) * CC + ch * 160 + r;
#pragma unroll
      for (int j = 0; j < 5; ++j) {
        const size_t idx = rowb + (size_t)(j * 32);
        const float s = acc[j][reg] + red[wn * 5120 + nl * 160 + j * 32 + r];
        out[idx] = g * s + x[idx];
      }
    }
  }
}

extern "C" void kernel_launch(void* const* d_in, const int* in_sizes, int n_in,
                              void* d_out, int out_size, void* d_ws, size_t ws_size,
                              hipStream_t stream) {
  const float* x     = (const float*)d_in[0];
  const float* Wq    = (const float*)d_in[1];
  const float* bq    = (const float*)d_in[2];
  const float* Wk    = (const float*)d_in[3];
  const float* bk    = (const float*)d_in[4];
  const float* Wv    = (const float*)d_in[5];
  const float* bv    = (const float*)d_in[6];
  const float* gamma = (const float*)d_in[7];
  float* out = (float*)d_out;

  char* w = (char*)d_ws;
  u16* X3   = (u16*)(w);                       // 512*40*32*8 (10485760 B)
  u16* W3   = (u16*)(w + 10485760);            // 14*40*32*8  (286720 B)
  u16* Qb   = (u16*)(w + 10772480);            // Q3: 8*64*8*32*8 (2097152 B)
  u16* Kb   = (u16*)(w + 12869632);            // 16384*64    (2097152 B)
  u16* Vt   = (u16*)(w + 14966784);            // V3: 8*256*320*8 (10485760 B)
  float* Lb = (float*)(w + 25452544);          // 16384 f32   (65536 B)

  cvt_blk<<<526, 256, 0, stream>>>(x, Wq, Wk, Wv, X3, W3);
  gemm_qkv<<<512, 256, 0, stream>>>(X3, W3, bq, bk, bv, Qb, Kb, Vt);
  row_stats<<<256, 512, 0, stream>>>(Qb, Kb, Lb);
  attn<<<512, 256, 0, stream>>>(Qb, Kb, Vt, Lb, x, gamma, out);
}

// Round 21
// 77.664 us; speedup vs baseline: 1.2627x; 1.0011x over previous
//
#include <hip/hip_runtime.h>
#include <hip/hip_bf16.h>

#define BB 8
#define NN 2048
#define CC 320
#define CQ 64
#define LOG2E 1.4426950408889634f

typedef __attribute__((ext_vector_type(8)))  short bf16x8;
typedef __attribute__((ext_vector_type(4)))  float f32x4;
typedef __attribute__((ext_vector_type(16))) float f32x16;
typedef __attribute__((ext_vector_type(4)))  unsigned short us4;
typedef __attribute__((ext_vector_type(8)))  unsigned short us8;
typedef __attribute__((ext_vector_type(4)))  unsigned int u32x4;
typedef unsigned short u16;

// Layouts:
//  X3[mt=m/32][kk8=k/8][ml=m%32][8]       (bf16; lane-contiguous A-frags)
//  W3[ct=c/32][kk8=k/8][cl=c%32][8]       (bf16; lane-contiguous B-frags)
//  Q3[b][kt=k/32][cq8=cq/8][kl=k%32][8]   (bf16, pre-scaled by log2e)
//  K3[b][nt=n/32][cq8=cq/8][nl=n%32][8]   (bf16; same blocked form as Q3)
//  V3[b][kt8=k/8][c][8]                   (bf16, UNSCALED — read-only)
//  Lb[b*N+k]                              (f32, log2 of softmax row sum)

static __device__ __forceinline__ u16 f2b(float f) {
  unsigned u = __builtin_bit_cast(unsigned, f);
  unsigned r = (u + 0x7FFFu + ((u >> 16) & 1u)) >> 16;
  return (u16)r;
}
static __device__ __forceinline__ float b2f(u16 s) {
  unsigned u = ((unsigned)s) << 16;
  return __builtin_bit_cast(float, u);
}

static __device__ __forceinline__ f32x16 zero16() {
  f32x16 v = {0,0,0,0, 0,0,0,0, 0,0,0,0, 0,0,0,0};
  return v;
}
static __device__ __forceinline__ f32x4 zero4() {
  f32x4 v = {0,0,0,0};
  return v;
}

static __device__ __forceinline__ void gll16(const void* g, void* l) {
  __builtin_amdgcn_global_load_lds(
      (const __attribute__((address_space(1))) unsigned int*)g,
      (__attribute__((address_space(3))) unsigned int*)l, 16, 0, 0);
}

// 8 fp32 -> bf16x8 via hardware packed converts (RNE, same as f2b)
static __device__ __forceinline__ bf16x8 cvt8(float4 a, float4 b) {
  unsigned p0, p1, p2, p3;
  asm("v_cvt_pk_bf16_f32 %0, %1, %2" : "=v"(p0) : "v"(a.x), "v"(a.y));
  asm("v_cvt_pk_bf16_f32 %0, %1, %2" : "=v"(p1) : "v"(a.z), "v"(a.w));
  asm("v_cvt_pk_bf16_f32 %0, %1, %2" : "=v"(p2) : "v"(b.x), "v"(b.y));
  asm("v_cvt_pk_bf16_f32 %0, %1, %2" : "=v"(p3) : "v"(b.z), "v"(b.w));
  u32x4 w = {p0, p1, p2, p3};
  return __builtin_bit_cast(bf16x8, w);
}

// ---------------------------------------------------------------------------
// K0: fused conversion. blocks 0..511: x -> X3; blocks 512..525: W -> W3.
// grid 526 x 256.
// ---------------------------------------------------------------------------
__global__ __launch_bounds__(256) void cvt_blk(const float* __restrict__ x,
                                               const float* __restrict__ Wq,
                                               const float* __restrict__ Wk,
                                               const float* __restrict__ Wv,
                                               u16* __restrict__ X3,
                                               u16* __restrict__ W3) {
  __shared__ float xs[32][324];   // +4 pad: conflict-free transpose reads
  const int t = threadIdx.x;
  const int bid = blockIdx.x;
  const bool isX = (bid < 512);
  const int b = isX ? bid : (bid - 512);
#pragma unroll
  for (int i = 0; i < 10; ++i) {
    const int lidx = i * 256 + t;        // 0..2559 float4 units
    const int m = lidx / 80;             // 80 float4 per row
    const int kq = lidx - m * 80;
    const float* src;
    if (isX) {
      src = x + (size_t)(b * 32 + m) * CC;
    } else {
      const int row = b * 32 + m;
      src = (row < 64) ? (Wq + (size_t)row * CC)
          : (row < 128) ? (Wk + (size_t)(row - 64) * CC)
                        : (Wv + (size_t)(row - 128) * CC);
    }
    float4 v = *(const float4*)(src + kq * 4);
    *(float4*)&xs[m][kq * 4] = v;
  }
  __syncthreads();
  u16* dst0 = (isX ? X3 : W3) + (size_t)b * 10240;
#pragma unroll
  for (int i = 0; i < 5; ++i) {
    const int u = i * 256 + t;           // 0..1279: kk8*32 + ml
    const int kk8 = u >> 5, ml = u & 31;
    float4 a = *(const float4*)&xs[ml][kk8 * 8];
    float4 c = *(const float4*)&xs[ml][kk8 * 8 + 4];
    bf16x8 o = cvt8(a, c);
    *(bf16x8*)(dst0 + (size_t)u * 8) = o;
  }
}

// ---------------------------------------------------------------------------
// K1: QKV GEMM, wide 128-col wave tiles (4 MFMA per 5 loads). XCD remap.
// grid 512 x 256: slot = colt(4) x yG(16); colt 3 covers only 2 tiles.
// Q -> Q3 blocked (log2e-scaled), K -> K3 blocked, V -> V3 blocked.
// ---------------------------------------------------------------------------
__global__ __launch_bounds__(256) void gemm_qkv(
    const u16* __restrict__ X3, const u16* __restrict__ W3,
    const float* __restrict__ bq, const float* __restrict__ bk,
    const float* __restrict__ bv,
    u16* __restrict__ Qb, u16* __restrict__ Kb, u16* __restrict__ Vt) {
  const int tid = threadIdx.x;
  const int lane = tid & 63, wid = tid >> 6;
  const int r = lane & 31, h = lane >> 5;
  const int bid = blockIdx.x;
  const int xcd = bid & 7;
  const int slot = bid >> 3;          // 0..63
  const int colt = slot & 3;          // 0..3
  const int yG = slot >> 2;           // 0..15
  const int ytile = yG * 8 + xcd;     // 0..127
  const int m0 = ytile * 128 + wid * 32;
  const int col0 = colt * 128;
  const int NT = (colt == 3) ? 2 : 4; // wave-uniform
  const int mt = m0 >> 5;

  const u16* abase = X3 + (size_t)mt * 10240 + (size_t)h * 256 + r * 8;
  const u16* bbase0 = W3 + (size_t)(colt * 4 + 0) * 10240 + (size_t)h * 256 + r * 8;
  const u16* bbase1 = bbase0 + 10240;
  const u16* bbase2 = bbase0 + 20480;
  const u16* bbase3 = bbase0 + 30720;

  f32x16 acc0 = zero16(), acc1 = zero16(), acc2 = zero16(), acc3 = zero16();
  bf16x8 a  = *(const bf16x8*)(abase);
  bf16x8 b0 = *(const bf16x8*)(bbase0);
  bf16x8 b1 = *(const bf16x8*)(bbase1);
  bf16x8 b2, b3;
  if (NT == 4) {
    b2 = *(const bf16x8*)(bbase2);
    b3 = *(const bf16x8*)(bbase3);
  }
#pragma unroll 1
  for (int ks = 0; ks < 20; ++ks) {
    bf16x8 na, nb0, nb1, nb2, nb3;
    if (ks < 19) {
      na  = *(const bf16x8*)(abase  + (ks + 1) * 512);
      nb0 = *(const bf16x8*)(bbase0 + (ks + 1) * 512);
      nb1 = *(const bf16x8*)(bbase1 + (ks + 1) * 512);
      if (NT == 4) {
        nb2 = *(const bf16x8*)(bbase2 + (ks + 1) * 512);
        nb3 = *(const bf16x8*)(bbase3 + (ks + 1) * 512);
      }
    }
    acc0 = __builtin_amdgcn_mfma_f32_32x32x16_bf16(a, b0, acc0, 0, 0, 0);
    acc1 = __builtin_amdgcn_mfma_f32_32x32x16_bf16(a, b1, acc1, 0, 0, 0);
    if (NT == 4) {
      acc2 = __builtin_amdgcn_mfma_f32_32x32x16_bf16(a, b2, acc2, 0, 0, 0);
      acc3 = __builtin_amdgcn_mfma_f32_32x32x16_bf16(a, b3, acc3, 0, 0, 0);
    }
    a = na; b0 = nb0; b1 = nb1;
    if (NT == 4) { b2 = nb2; b3 = nb3; }
  }

  const int bb = m0 >> 11;        // batch
  const int mloc = m0 & 2047;     // n (or k) within batch

#pragma unroll
  for (int nt = 0; nt < 4; ++nt) {
    if (nt >= NT) continue;
    const int tb = col0 + nt * 32;      // tile base column (uniform)
    const int col = tb + r;
    const f32x16 A = (nt == 0) ? acc0 : (nt == 1) ? acc1 : (nt == 2) ? acc2 : acc3;
    if (tb >= 128) {
      // V3[b][kt8][c][8]
      const int c = col - 128;
      const float bias = bv[c];
      u16* vdst = Vt + (((size_t)(bb * 256 + (mloc >> 3)) * 320 + c) * 8) + 4 * h;
#pragma unroll
      for (int g = 0; g < 4; ++g) {
        us4 o;
#pragma unroll
        for (int e = 0; e < 4; ++e) o[e] = f2b(A[g * 4 + e] + bias);
        *(us4*)(vdst + (size_t)g * 2560) = o;
      }
    } else if (tb >= 64) {
      // K3[b][nt][cq8][nl][8] — same blocked form as Q3, bias bk, no log2e
      const float bias = bk[col - 64];
      const int kt = mloc >> 5;
      const int cq = col - 64;
      u16* kdst = Kb + (((size_t)(bb * 64 + kt) * 8 + (cq >> 3)) * 32) * 8 + (cq & 7);
#pragma unroll
      for (int reg = 0; reg < 16; ++reg) {
        const int kl = (reg & 3) + 8 * (reg >> 2) + 4 * h;
        kdst[kl * 8] = f2b(A[reg] + bias);
      }
    } else {
      const float bias = bq[col];
      const int kt = mloc >> 5;
      u16* qdst = Qb + (((size_t)(bb * 64 + kt) * 8 + (col >> 3)) * 32) * 8 + (col & 7);
#pragma unroll
      for (int reg = 0; reg < 16; ++reg) {
        const int kl = (reg & 3) + 8 * (reg >> 2) + 4 * h;
        qdst[kl * 8] = f2b((A[reg] + bias) * LOG2E);
      }
    }
  }
}

// ---------------------------------------------------------------------------
// K3: row sums -> Lb[k] = log2(S[k]). 8 waves (512 thr), grid 256.
// B-frags now from blocked K3 (lane-contiguous: 4 lines/instr, was 16).
// ---------------------------------------------------------------------------
__global__ __launch_bounds__(512) void row_stats(
    const u16* __restrict__ Qb, const u16* __restrict__ Kb,
    float* __restrict__ Lb) {
  __shared__ float Sp[8][64];
  const int tid = threadIdx.x;
  const int lane = tid & 63, wid = tid >> 6;   // 0..7
  const int rl = lane & 15, hq = lane >> 4;
  const int bid = blockIdx.x;
  const int batch = bid & 7;
  const int kloc64 = (bid >> 3) * 64;          // bid>>3 in [0,32)

  bf16x8 af[4][2];
#pragma unroll
  for (int mt = 0; mt < 4; ++mt) {
    const int k_loc = kloc64 + mt * 16 + rl;
    const int kt = k_loc >> 5, kl = k_loc & 31;
#pragma unroll
    for (int qs = 0; qs < 2; ++qs)
      af[mt][qs] = *(const bf16x8*)(Qb +
          (((size_t)(batch * 64 + kt) * 8 + qs * 4 + hq) * 32 + kl) * 8);
  }

  float S[4][4];
#pragma unroll
  for (int mt = 0; mt < 4; ++mt)
#pragma unroll
    for (int rr = 0; rr < 4; ++rr) S[mt][rr] = 0.f;

  // K3 base for this wave's m-range: rows wid*256 + ms*16 + rl of this batch.
  // kt = wid*8 + (ms>>1); kl = (ms&1)*16 + rl.
  // c0: cq8 = hq; c1: cq8 = 4 + hq.
  const u16* krbase = Kb + (size_t)(batch * 64 + wid * 8) * 2048
                         + (size_t)hq * 256 + rl * 8;
#define KOFF(MS) ((size_t)((MS) >> 1) * 2048 + ((MS) & 1) * 128)
  bf16x8 c0 = *(const bf16x8*)(krbase + KOFF(0));
  bf16x8 c1 = *(const bf16x8*)(krbase + KOFF(0) + 1024);
#pragma unroll 1
  for (int ms = 0; ms < 16; ++ms) {
    bf16x8 n0, n1;
    if (ms < 15) {
      n0 = *(const bf16x8*)(krbase + KOFF(ms + 1));
      n1 = *(const bf16x8*)(krbase + KOFF(ms + 1) + 1024);
    }
#pragma unroll
    for (int mt = 0; mt < 4; ++mt) {
      f32x4 e = zero4();
      e = __builtin_amdgcn_mfma_f32_16x16x32_bf16(af[mt][0], c0, e, 0, 0, 0);
      e = __builtin_amdgcn_mfma_f32_16x16x32_bf16(af[mt][1], c1, e, 0, 0, 0);
#pragma unroll
      for (int rr = 0; rr < 4; ++rr) S[mt][rr] += __builtin_amdgcn_exp2f(e[rr]);
    }
    c0 = n0; c1 = n1;
  }
#undef KOFF

#pragma unroll
  for (int d = 1; d < 16; d <<= 1)
#pragma unroll
    for (int mt = 0; mt < 4; ++mt)
#pragma unroll
      for (int rr = 0; rr < 4; ++rr) S[mt][rr] += __shfl_xor(S[mt][rr], d, 64);

  if (rl == 0) {
#pragma unroll
    for (int mt = 0; mt < 4; ++mt)
#pragma unroll
      for (int rr = 0; rr < 4; ++rr) Sp[wid][mt * 16 + hq * 4 + rr] = S[mt][rr];
  }
  __syncthreads();
  if (tid < 64) {
    float s = 0.f;
#pragma unroll
    for (int p = 0; p < 8; ++p) s += Sp[p][tid];
    Lb[batch * NN + kloc64 + tid] = __log2f(s);
  }
}

// ---------------------------------------------------------------------------
// K4: attention v13 (r18-passing) — kf loads adapted to blocked K3 (one-time,
// lane-contiguous). Everything else byte-identical to r20.
// ---------------------------------------------------------------------------
__global__ __launch_bounds__(256, 2) void attn(
    const u16* __restrict__ Qb, const u16* __restrict__ Kb,
    const u16* __restrict__ Vt, const float* __restrict__ Lb,
    const float* __restrict__ x, const float* __restrict__ gamma,
    float* __restrict__ out) {
  __shared__ __align__(16) char LDSRAW[49152];   // 40KB V bufs + 8KB L
  float* Ls = (float*)(LDSRAW + 40960);          // [2048] = both kh halves
  const int tid = threadIdx.x;
  const int lane = tid & 63, wid = tid >> 6;
  const int wn = wid >> 1;       // n-tile within pair
  const int kh = wid & 1;        // k-half
  const int r = lane & 31, h = lane >> 5;
  const int bid = blockIdx.x;
  const int b = bid & 7;
  const int rest = bid >> 3;
  const int ch = rest & 1;
  const int n0 = (rest >> 1) * 64;

  // one-time: stage this batch's L (2048 f32, 8 KB) into LDS
#pragma unroll
  for (int i = 0; i < 8; ++i)
    Ls[i * 256 + tid] = Lb[b * NN + i * 256 + tid];

  // K fragments for n-tile n0 + wn*32 (held all k), from blocked K3:
  // kf[qs] covers cq = qs*16 + h*8 -> cq8 = qs*2 + h; nl = r.
  bf16x8 kf[4];
  {
    const u16* krow3 = Kb + (size_t)(b * 64 + ((n0 >> 5) + wn)) * 2048
                          + (size_t)h * 256 + r * 8;
#pragma unroll
    for (int qs = 0; qs < 4; ++qs)
      kf[qs] = *(const bf16x8*)(krow3 + qs * 512);
  }

  f32x16 acc[5];
#pragma unroll
  for (int j = 0; j < 5; ++j) acc[j] = zero16();

  // per-wave bases for this k-half
  const u16* qb3 = Qb + ((size_t)(b * 64 + kh * 32) * 8) * 256 + (size_t)r * 8;
  const float* lsb = Ls + kh * 1024 + 4 * h;   // LDS pointer (per-lane via h)

  // stage V only: 20 chunks of 1KB (10 per kh), wave w takes [w*5, w*5+5)
#define STAGE(TN, BUF) {                                                       \
    _Pragma("unroll")                                                          \
    for (int i_ = 0; i_ < 5; ++i_) {                                           \
      const int c_ = wid * 5 + i_;                                             \
      const int khc_ = c_ / 10;                                                \
      const int rem_ = c_ % 10;                                                \
      char* dst_ = LDSRAW + (BUF) * 20480 + khc_ * 10240 + rem_ * 1024;        \
      const int off_ = rem_ * 512 + lane * 8;                                  \
      const int row_ = off_ / 1280;                                            \
      const int win_ = off_ - row_ * 1280;                                     \
      const u16* src_ = Vt +                                                   \
          ((size_t)(b * 256 + khc_ * 128 + (TN) * 4 + row_) * 320              \
           + ch * 160) * 8 + win_;                                             \
      gll16(src_, dst_);                                                       \
    }                                                                          \
  }

// prefetch Q frags for tile TN into QN (plain global loads, lane-contiguous)
#define LQ(QN, TN) {                                                           \
    _Pragma("unroll")                                                          \
    for (int qs = 0; qs < 4; ++qs)                                             \
      QN[qs] = *(const bf16x8*)(qb3 + ((size_t)(TN) * 8 + qs * 2 + h) * 256);  \
  }

// compute tile T from LDS buffer BUF using prefetched QF; prefetch QN (TNX);
// L read from LDS (broadcast ds_read, lgkm queue)
#define COMPUTE(T, BUF, QF, QN, TNX) {                                         \
    LQ(QN, TNX)                                                                \
    float4 LF0 = *(const float4*)(lsb + (T) * 32);                             \
    float4 LF1 = *(const float4*)(lsb + (T) * 32 + 8);                         \
    float4 LF2 = *(const float4*)(lsb + (T) * 32 + 16);                        \
    float4 LF3 = *(const float4*)(lsb + (T) * 32 + 24);                        \
    const char* base_ = LDSRAW + (BUF) * 20480 + kh * 10240;                   \
    f32x16 e = zero16();                                                       \
    _Pragma("unroll")                                                          \
    for (int qs = 0; qs < 4; ++qs)                                             \
      e = __builtin_amdgcn_mfma_f32_32x32x16_bf16(QF[qs], kf[qs], e, 0, 0, 0); \
    bf16x8 vf[5][2];                                                           \
    _Pragma("unroll")                                                          \
    for (int j = 0; j < 5; ++j)                                                \
      _Pragma("unroll")                                                        \
      for (int ks = 0; ks < 2; ++ks)                                           \
        vf[j][ks] = *(const bf16x8*)(base_ + (ks * 2 + h) * 2560               \
                                     + (j * 32 + r) * 16);                     \
    unsigned pk0, pk1, pk2, pk3, pk4, pk5, pk6, pk7;                           \
    { float l0 = __builtin_amdgcn_exp2f(e[0]  - LF0.x);                        \
      float h0 = __builtin_amdgcn_exp2f(e[1]  - LF0.y);                        \
      float l1 = __builtin_amdgcn_exp2f(e[2]  - LF0.z);                        \
      float h1 = __builtin_amdgcn_exp2f(e[3]  - LF0.w);                        \
      float l2 = __builtin_amdgcn_exp2f(e[4]  - LF1.x);                        \
      float h2 = __builtin_amdgcn_exp2f(e[5]  - LF1.y);                        \
      float l3 = __builtin_amdgcn_exp2f(e[6]  - LF1.z);                        \
      float h3 = __builtin_amdgcn_exp2f(e[7]  - LF1.w);                        \
      float l4 = __builtin_amdgcn_exp2f(e[8]  - LF2.x);                        \
      float h4 = __builtin_amdgcn_exp2f(e[9]  - LF2.y);                        \
      float l5 = __builtin_amdgcn_exp2f(e[10] - LF2.z);                        \
      float h5 = __builtin_amdgcn_exp2f(e[11] - LF2.w);                        \
      float l6 = __builtin_amdgcn_exp2f(e[12] - LF3.x);                        \
      float h6 = __builtin_amdgcn_exp2f(e[13] - LF3.y);                        \
      float l7 = __builtin_amdgcn_exp2f(e[14] - LF3.z);                        \
      float h7 = __builtin_amdgcn_exp2f(e[15] - LF3.w);                        \
      asm("v_cvt_pk_bf16_f32 %0, %1, %2" : "=v"(pk0) : "v"(l0), "v"(h0));      \
      asm("v_cvt_pk_bf16_f32 %0, %1, %2" : "=v"(pk1) : "v"(l1), "v"(h1));      \
      asm("v_cvt_pk_bf16_f32 %0, %1, %2" : "=v"(pk2) : "v"(l2), "v"(h2));      \
      asm("v_cvt_pk_bf16_f32 %0, %1, %2" : "=v"(pk3) : "v"(l3), "v"(h3));      \
      asm("v_cvt_pk_bf16_f32 %0, %1, %2" : "=v"(pk4) : "v"(l4), "v"(h4));      \
      asm("v_cvt_pk_bf16_f32 %0, %1, %2" : "=v"(pk5) : "v"(l5), "v"(h5));      \
      asm("v_cvt_pk_bf16_f32 %0, %1, %2" : "=v"(pk6) : "v"(l6), "v"(h6));      \
      asm("v_cvt_pk_bf16_f32 %0, %1, %2" : "=v"(pk7) : "v"(l7), "v"(h7)); }    \
    asm("v_permlane32_swap_b32 %0, %1" : "+v"(pk0), "+v"(pk2));                \
    asm("v_permlane32_swap_b32 %0, %1" : "+v"(pk1), "+v"(pk3));                \
    asm("v_permlane32_swap_b32 %0, %1" : "+v"(pk4), "+v"(pk6));                \
    asm("v_permlane32_swap_b32 %0, %1" : "+v"(pk5), "+v"(pk7));                \
    u32x4 w0_ = {pk0, pk1, pk2, pk3};                                          \
    u32x4 w1_ = {pk4, pk5, pk6, pk7};                                          \
    bf16x8 pa0 = __builtin_bit_cast(bf16x8, w0_);                              \
    bf16x8 pa1 = __builtin_bit_cast(bf16x8, w1_);                              \
    __builtin_amdgcn_s_setprio(1);                                             \
    _Pragma("unroll")                                                          \
    for (int j = 0; j < 5; ++j) {                                              \
      acc[j] = __builtin_amdgcn_mfma_f32_32x32x16_bf16(pa0, vf[j][0], acc[j], 0, 0, 0); \
      acc[j] = __builtin_amdgcn_mfma_f32_32x32x16_bf16(pa1, vf[j][1], acc[j], 0, 0, 0); \
    }                                                                          \
    __builtin_amdgcn_s_setprio(0);                                             \
  }

  bf16x8 qfA[4], qfB[4];

  STAGE(0, 0);
  LQ(qfA, 0)
  __syncthreads();                 // V tile 0 staged + Ls filled (all waves)
#pragma unroll 1
  for (int t = 0; t < 32; t += 2) {
    STAGE(t + 1, 1);                          // odd tile -> buf1
    COMPUTE(t, 0, qfA, qfB, t + 1);           // even tile from buf0
    __syncthreads();
    if (t + 2 < 32) STAGE(t + 2, 0);          // even tile -> buf0
    COMPUTE(t + 1, 1, qfB, qfA, (t + 2) & 31);// odd tile from buf1
    __syncthreads();
  }
#undef STAGE
#undef LQ
#undef COMPUTE

  // kh=1 waves dump partial sums; kh=0 waves combine and write out
  float* red = (float*)LDSRAW;   // 2 regions x 5120 f32 = 40960 B (fits)
  if (kh == 1) {
#pragma unroll
    for (int reg = 0; reg < 16; ++reg) {
      const int nl = (reg & 3) + 8 * (reg >> 2) + 4 * h;
#pragma unroll
      for (int j = 0; j < 5; ++j)
        red[wn * 5120 + nl * 160 + j * 32 + r] = acc[j][reg];
    }
  }
  __syncthreads();
  if (kh == 0) {
    const float g = gamma[0];
#pragma unroll
    for (int reg = 0; reg < 16; ++reg) {
      const int nl = (reg & 3) + 8 * (reg >> 2) + 4 * h;
      const size_t rowb = ((size_t)(b * NN) + n0 + wn * 32 + nl) * CC + ch * 160 + r;
#pragma unroll
      for (int j = 0; j < 5; ++j) {
        const size_t idx = rowb + (size_t)(j * 32);
        const float s = acc[j][reg] + red[wn * 5120 + nl * 160 + j * 32 + r];
        out[idx] = g * s + x[idx];
      }
    }
  }
}

extern "C" void kernel_launch(void* const* d_in, const int* in_sizes, int n_in,
                              void* d_out, int out_size, void* d_ws, size_t ws_size,
                              hipStream_t stream) {
  const float* x     = (const float*)d_in[0];
  const float* Wq    = (const float*)d_in[1];
  const float* bq    = (const float*)d_in[2];
  const float* Wk    = (const float*)d_in[3];
  const float* bk    = (const float*)d_in[4];
  const float* Wv    = (const float*)d_in[5];
  const float* bv    = (const float*)d_in[6];
  const float* gamma = (const float*)d_in[7];
  float* out = (float*)d_out;

  char* w = (char*)d_ws;
  u16* X3   = (u16*)(w);                       // 512*40*32*8 (10485760 B)
  u16* W3   = (u16*)(w + 10485760);            // 14*40*32*8  (286720 B)
  u16* Qb   = (u16*)(w + 10772480);            // Q3: 8*64*8*32*8 (2097152 B)
  u16* Kb   = (u16*)(w + 12869632);            // K3: 8*64*8*32*8 (2097152 B)
  u16* Vt   = (u16*)(w + 14966784);            // V3: 8*256*320*8 (10485760 B)
  float* Lb = (float*)(w + 25452544);          // 16384 f32   (65536 B)

  cvt_blk<<<526, 256, 0, stream>>>(x, Wq, Wk, Wv, X3, W3);
  gemm_qkv<<<512, 256, 0, stream>>>(X3, W3, bq, bk, bv, Qb, Kb, Vt);
  row_stats<<<256, 512, 0, stream>>>(Qb, Kb, Lb);
  attn<<<512, 256, 0, stream>>>(Qb, Kb, Vt, Lb, x, gamma, out);
}